// Round 1
// baseline (14685.387 us; speedup 1.0000x reference)
//
#include <hip/hip_runtime.h>
#include <hip/hip_bf16.h>
#include <stdint.h>
#include <stddef.h>

namespace {

constexpr int CB = 32;                  // batch
constexpr int CS = 4;                   // states
constexpr int CV = 20000;               // vocab
constexpr int CH = 512;                 // hidden
constexpr int CBEAM = 5;
constexpr int CT = 20;                  // MAX_STEPS
constexpr int CNR = CB * CS * CBEAM;    // 640 rows
constexpr int CSB = CS * CBEAM;         // 20
constexpr int CNM = CB * CS * CS * CV;  // 10,240,000 mask elems
constexpr float VNF = -1e20f;
constexpr float NEGINF = -3.402823466e+38f;
constexpr int IMAX = 0x7fffffff;

// ---------------- state_transform dtype detection ----------------
// modes: 0=u8/bool bytes, 1=int32, 2=int64(low word), 3=float32
__global__ void detect_mode_k(const unsigned int* __restrict__ w, int* __restrict__ mode) {
  if (threadIdx.x != 0 || blockIdx.x != 0) return;
  int all01 = 1, odd1 = 0, f1 = 0;
  for (int i = 0; i < 256; ++i) {
    unsigned int x = w[i];
    if (x > 1u) all01 = 0;
    if ((i & 1) && x == 1u) odd1++;
    if (x == 0x3f800000u) f1++;
  }
  int md;
  if (f1 > 128) md = 3;
  else if (all01) md = (odd1 > 8) ? 1 : 2;
  else md = 0;
  *mode = md;
}

__global__ void convert_mask_k(const void* __restrict__ st, unsigned char* __restrict__ m,
                               const int* __restrict__ mode) {
  int md = *mode;
  for (int i = blockIdx.x * blockDim.x + threadIdx.x; i < CNM; i += gridDim.x * blockDim.x) {
    unsigned char r;
    if (md == 0)      r = ((const unsigned char*)st)[i] != 0;
    else if (md == 1) r = ((const unsigned int*)st)[i] != 0;
    else if (md == 2) r = ((const unsigned int*)st)[2 * (size_t)i] != 0;
    else              r = (((const unsigned int*)st)[i] & 0x7fffffffu) != 0;
    m[i] = r;
  }
}

// ---------------- img @ W_im (step-invariant) ----------------
__global__ __launch_bounds__(256) void img_proj_k(const float* __restrict__ img,
                                                  const float* __restrict__ Wim,
                                                  float* __restrict__ out) {
  int b = blockIdx.x, tid = threadIdx.x;
  __shared__ float simg[2048];
  for (int i = tid; i < 2048; i += 256) simg[i] = img[b * 2048 + i];
  __syncthreads();
  int c0 = tid * 2;
  float a0 = 0.f, a1 = 0.f;
  for (int k = 0; k < 2048; ++k) {
    float x = simg[k];
    float2 w = *(const float2*)&Wim[(size_t)k * CH + c0];
    a0 = fmaf(x, w.x, a0);
    a1 = fmaf(x, w.y, a1);
  }
  out[b * CH + c0] = a0;
  out[b * CH + c0 + 1] = a1;
}

// ---------------- h0 = tanh(emb[start] + img_proj) ----------------
__global__ void init_h_k(const float* __restrict__ emb, const int* __restrict__ start,
                         const float* __restrict__ imgp, float* __restrict__ H0) {
  int b = blockIdx.x, tid = threadIdx.x;
  int tok = start[b];
  for (int c = tid; c < CH; c += 256)
    H0[b * CH + c] = tanhf(emb[(size_t)tok * CH + c] + imgp[b * CH + c]);
}

// ---------------- generic tiled f32 GEMM, optional row gather + tanh/emb/img epilogue ----
// C[row][col] = dot(A[rowmap[row]], B[:,col]) ; EPI==1 adds emb/img + tanh
template <int BM, int BN, int KB, int MT, int NT, int EPI>
__global__ __launch_bounds__(256) void gemm_k(
    const float* __restrict__ A, const int* __restrict__ rowmap,
    const float* __restrict__ Bm, float* __restrict__ C,
    int M, int N, int K,
    const int* __restrict__ tok, const float* __restrict__ emb,
    const float* __restrict__ imgp) {
  constexpr int TX = BN / NT;
  constexpr int TY = BM / MT;
  static_assert(TX * TY == 256, "thread count");
  static_assert((BM * KB / 4) % 256 == 0 && (KB * BN / 4) % 256 == 0, "stage");
  __shared__ float As[KB][BM + 4];
  __shared__ float Bs[KB][BN + 4];
  const int bm = blockIdx.y * BM;
  const int bn = blockIdx.x * BN;
  const int tid = threadIdx.x;
  const int tx = tid % TX, ty = tid / TX;
  float acc[MT][NT];
#pragma unroll
  for (int i = 0; i < MT; ++i)
#pragma unroll
    for (int j = 0; j < NT; ++j) acc[i][j] = 0.f;

  for (int k0 = 0; k0 < K; k0 += KB) {
    constexpr int AIT = BM * KB / 4 / 256;
#pragma unroll
    for (int it = 0; it < AIT; ++it) {
      int i = tid + it * 256;
      int r = i / (KB / 4);
      int kq = i % (KB / 4);
      int row = bm + r;
      float4 v = make_float4(0.f, 0.f, 0.f, 0.f);
      if (row < M) {
        int sr = rowmap ? rowmap[row] : row;
        v = *(const float4*)&A[(size_t)sr * K + k0 + kq * 4];
      }
      As[kq * 4 + 0][r] = v.x;
      As[kq * 4 + 1][r] = v.y;
      As[kq * 4 + 2][r] = v.z;
      As[kq * 4 + 3][r] = v.w;
    }
    constexpr int BIT = KB * BN / 4 / 256;
#pragma unroll
    for (int it = 0; it < BIT; ++it) {
      int i = tid + it * 256;
      int kk = i / (BN / 4);
      int cq = i % (BN / 4);
      int col = bn + cq * 4;
      float4 v = make_float4(0.f, 0.f, 0.f, 0.f);
      if (col < N) v = *(const float4*)&Bm[(size_t)(k0 + kk) * N + col];
      *(float4*)&Bs[kk][cq * 4] = v;
    }
    __syncthreads();
#pragma unroll 8
    for (int kk = 0; kk < KB; ++kk) {
      float a[MT], bb[NT];
#pragma unroll
      for (int i = 0; i < MT; ++i) a[i] = As[kk][ty * MT + i];
#pragma unroll
      for (int j = 0; j < NT; ++j) bb[j] = Bs[kk][tx * NT + j];
#pragma unroll
      for (int i = 0; i < MT; ++i)
#pragma unroll
        for (int j = 0; j < NT; ++j) acc[i][j] = fmaf(a[i], bb[j], acc[i][j]);
    }
    __syncthreads();
  }
#pragma unroll
  for (int i = 0; i < MT; ++i) {
    int row = bm + ty * MT + i;
    if (row < M) {
#pragma unroll
      for (int j4 = 0; j4 < NT / 4; ++j4) {
        int col = bn + tx * NT + j4 * 4;
        if (col < N) {
          float4 v;
          v.x = acc[i][j4 * 4 + 0];
          v.y = acc[i][j4 * 4 + 1];
          v.z = acc[i][j4 * 4 + 2];
          v.w = acc[i][j4 * 4 + 3];
          if (EPI == 1) {
            size_t eb = (size_t)tok[row] * N;
            int ib = (row / CSB) * N;
            v.x = tanhf(v.x + emb[eb + col + 0] + imgp[ib + col + 0]);
            v.y = tanhf(v.y + emb[eb + col + 1] + imgp[ib + col + 1]);
            v.z = tanhf(v.z + emb[eb + col + 2] + imgp[ib + col + 2]);
            v.w = tanhf(v.w + emb[eb + col + 3] + imgp[ib + col + 3]);
          }
          *(float4*)&C[(size_t)row * N + col] = v;
        }
      }
    }
  }
}

// ---------------- per-row logsumexp over V ----------------
__global__ __launch_bounds__(256) void lse_k(const float* __restrict__ logits,
                                             float* __restrict__ lse) {
  int row = blockIdx.x;
  int tid = threadIdx.x;
  const float* lp = logits + (size_t)row * CV;
  __shared__ float red[4];
  float m = NEGINF;
  for (int v = tid * 4; v < CV; v += 1024) {
    float4 x = *(const float4*)(lp + v);
    m = fmaxf(m, fmaxf(fmaxf(x.x, x.y), fmaxf(x.z, x.w)));
  }
#pragma unroll
  for (int off = 32; off > 0; off >>= 1) m = fmaxf(m, __shfl_xor(m, off));
  if ((tid & 63) == 0) red[tid >> 6] = m;
  __syncthreads();
  m = fmaxf(fmaxf(red[0], red[1]), fmaxf(red[2], red[3]));
  __syncthreads();
  float s = 0.f;
  for (int v = tid * 4; v < CV; v += 1024) {
    float4 x = *(const float4*)(lp + v);
    s += expf(x.x - m) + expf(x.y - m) + expf(x.z - m) + expf(x.w - m);
  }
#pragma unroll
  for (int off = 32; off > 0; off >>= 1) s += __shfl_xor(s, off);
  if ((tid & 63) == 0) red[tid >> 6] = s;
  __syncthreads();
  if (tid == 0) lse[row] = m + logf(red[0] + red[1] + red[2] + red[3]);
}

// ---------------- stable insertion into 5 sorted regs (val desc, idx asc) --------
__device__ __forceinline__ void ins5(float val, int idx, float& v0, float& v1, float& v2,
                                     float& v3, float& v4, int& i0, int& i1, int& i2,
                                     int& i3, int& i4) {
  if (!(val > v4)) return;  // ties drop (stable: later index goes after)
  if (val > v0) {
    v4 = v3; i4 = i3; v3 = v2; i3 = i2; v2 = v1; i2 = i1; v1 = v0; i1 = i0; v0 = val; i0 = idx;
  } else if (val > v1) {
    v4 = v3; i4 = i3; v3 = v2; i3 = i2; v2 = v1; i2 = i1; v1 = val; i1 = idx;
  } else if (val > v2) {
    v4 = v3; i4 = i3; v3 = v2; i3 = i2; v2 = val; i2 = idx;
  } else if (val > v3) {
    v4 = v3; i4 = i3; v3 = val; i3 = idx;
  } else {
    v4 = val; i4 = idx;
  }
}

// merge two sorted 5-lists in LDS (dst <- merge(dst, src)), order (val desc, idx asc)
__device__ __forceinline__ void merge5(float* sv, int* si, int dst, int src) {
  float a0 = sv[dst * 5 + 0], a1 = sv[dst * 5 + 1], a2 = sv[dst * 5 + 2],
        a3 = sv[dst * 5 + 3], a4 = sv[dst * 5 + 4];
  int ai0 = si[dst * 5 + 0], ai1 = si[dst * 5 + 1], ai2 = si[dst * 5 + 2],
      ai3 = si[dst * 5 + 3], ai4 = si[dst * 5 + 4];
  float b0 = sv[src * 5 + 0], b1 = sv[src * 5 + 1], b2 = sv[src * 5 + 2],
        b3 = sv[src * 5 + 3], b4 = sv[src * 5 + 4];
  int bi0 = si[src * 5 + 0], bi1 = si[src * 5 + 1], bi2 = si[src * 5 + 2],
      bi3 = si[src * 5 + 3], bi4 = si[src * 5 + 4];
  float o0, o1, o2, o3, o4;
  int q0, q1, q2, q3, q4;
#define MSTEP(OV, OI)                                                                   \
  {                                                                                     \
    bool ta = (a0 > b0) || (a0 == b0 && ai0 < bi0);                                     \
    if (ta) {                                                                           \
      OV = a0; OI = ai0;                                                                \
      a0 = a1; ai0 = ai1; a1 = a2; ai1 = ai2; a2 = a3; ai2 = ai3; a3 = a4; ai3 = ai4;   \
      a4 = NEGINF; ai4 = IMAX;                                                          \
    } else {                                                                            \
      OV = b0; OI = bi0;                                                                \
      b0 = b1; bi0 = bi1; b1 = b2; bi1 = bi2; b2 = b3; bi2 = bi3; b3 = b4; bi3 = bi4;   \
      b4 = NEGINF; bi4 = IMAX;                                                          \
    }                                                                                   \
  }
  MSTEP(o0, q0) MSTEP(o1, q1) MSTEP(o2, q2) MSTEP(o3, q3) MSTEP(o4, q4)
#undef MSTEP
  sv[dst * 5 + 0] = o0; sv[dst * 5 + 1] = o1; sv[dst * 5 + 2] = o2;
  sv[dst * 5 + 3] = o3; sv[dst * 5 + 4] = o4;
  si[dst * 5 + 0] = q0; si[dst * 5 + 1] = q1; si[dst * 5 + 2] = q2;
  si[dst * 5 + 3] = q3; si[dst * 5 + 4] = q4;
}

// ---------------- masked top-5 over vocab ----------------
// non-INIT: block = ((b*S+st)*S+ss)*BEAM+beam ; writes top_lp/top_cls
// INIT:     block = b*S+st (ss=0, row=b) ; writes LP0/preds0/last_preds/rowmap directly
template <bool INIT>
__global__ __launch_bounds__(256) void topk_k(
    const float* __restrict__ logits, const float* __restrict__ lse,
    const unsigned char* __restrict__ mask, const int* __restrict__ last_preds,
    float* __restrict__ top_lp, int* __restrict__ top_cls,
    float* __restrict__ lp0, int* __restrict__ preds0,
    int* __restrict__ lastp_out, int* __restrict__ rowmap) {
  int blk = blockIdx.x;
  int b, st, ss, lrow;
  if (INIT) {
    b = blk / CS; st = blk % CS; ss = 0; lrow = b;
  } else {
    int beam = blk % CBEAM;
    ss = (blk / CBEAM) % CS;
    st = (blk / (CBEAM * CS)) % CS;
    b = blk / (CBEAM * CS * CS);
    lrow = (b * CS + ss) * CBEAM + beam;
  }
  const unsigned char* mrow = mask + (size_t)((b * CS + ss) * CS + st) * CV;
  int tid = threadIdx.x;

  if (!INIT) {
    if (last_preds[lrow] == 0) {  // ended beam: cleaned = after_end
      if (tid == 0) {
        top_lp[blk * 5 + 0] = mrow[0] ? 0.0f : VNF;
        top_cls[blk * 5 + 0] = 0;
#pragma unroll
        for (int k = 1; k < 5; ++k) {
          top_lp[blk * 5 + k] = VNF;
          top_cls[blk * 5 + k] = k;
        }
      }
      return;
    }
  }

  const float* lprow = logits + (size_t)lrow * CV;
  float lsev = lse[lrow];
  float v0 = NEGINF, v1 = NEGINF, v2 = NEGINF, v3 = NEGINF, v4 = NEGINF;
  int i0 = IMAX, i1 = IMAX, i2 = IMAX, i3 = IMAX, i4 = IMAX;
  for (int base = tid * 4; base < CV; base += 1024) {
    float4 x = *(const float4*)(lprow + base);
    unsigned int mm = *(const unsigned int*)(mrow + base);
    float xs[4] = {x.x, x.y, x.z, x.w};
#pragma unroll
    for (int j = 0; j < 4; ++j) {
      float val = ((mm >> (8 * j)) & 0xffu) ? (xs[j] - lsev) : VNF;
      ins5(val, base + j, v0, v1, v2, v3, v4, i0, i1, i2, i3, i4);
    }
  }
  __shared__ float sv[256 * 5];
  __shared__ int si[256 * 5];
  sv[tid * 5 + 0] = v0; sv[tid * 5 + 1] = v1; sv[tid * 5 + 2] = v2;
  sv[tid * 5 + 3] = v3; sv[tid * 5 + 4] = v4;
  si[tid * 5 + 0] = i0; si[tid * 5 + 1] = i1; si[tid * 5 + 2] = i2;
  si[tid * 5 + 3] = i3; si[tid * 5 + 4] = i4;
  for (int stride = 128; stride > 0; stride >>= 1) {
    __syncthreads();
    if (tid < stride) merge5(sv, si, tid, tid + stride);
  }
  __syncthreads();
  if (tid == 0) {
    if (INIT) {
#pragma unroll
      for (int k = 0; k < 5; ++k) {
        int slot = blk * 5 + k;  // = b*20 + st*5 + k
        lp0[slot] = sv[k];
        preds0[slot] = si[k];
        lastp_out[slot] = si[k];
        rowmap[slot] = b;
      }
    } else {
#pragma unroll
      for (int k = 0; k < 5; ++k) {
        top_lp[blk * 5 + k] = sv[k];
        top_cls[blk * 5 + k] = si[k];
      }
    }
  }
}

// ---------------- beam selection: top-5 of 100 candidates per (b, st) ----------------
__global__ __launch_bounds__(128) void beam_sel_k(
    const float* __restrict__ top_lp, const int* __restrict__ top_cls,
    const float* __restrict__ lp_old, float* __restrict__ lp_new,
    int* __restrict__ last_preds, int* __restrict__ rowmap,
    int* __restrict__ preds_t, int* __restrict__ bps_t) {
  int b = blockIdx.x / CS, st = blockIdx.x % CS;
  int tid = threadIdx.x;
  __shared__ float sv[128];
  __shared__ int si[128];
  float val = NEGINF;
  int idx = IMAX;
  if (tid < 100) {
    int ss = tid / 25, rem = tid % 25;
    int beam = rem / 5, k = rem % 5;
    val = top_lp[(size_t)(((b * CS + st) * CS + ss) * CBEAM + beam) * 5 + k] +
          lp_old[(b * CS + ss) * CBEAM + beam];
    idx = tid;
  }
  for (int r = 0; r < 5; ++r) {
    sv[tid] = val;
    si[tid] = idx;
    __syncthreads();
    for (int off = 64; off > 0; off >>= 1) {
      if (tid < off) {
        float w = sv[tid + off];
        int wi = si[tid + off];
        if (w > sv[tid] || (w == sv[tid] && wi < si[tid])) { sv[tid] = w; si[tid] = wi; }
      }
      __syncthreads();
    }
    float wval = sv[0];
    int widx = si[0];
    if (idx == widx) { val = NEGINF; idx = IMAX; }
    if (tid == r) {
      int ss = widx / 25, rem = widx % 25;
      int beam = rem / 5, k = rem % 5;
      int pred = top_cls[(size_t)(((b * CS + st) * CS + ss) * CBEAM + beam) * 5 + k];
      int bp = widx / 5;  // ss*5+beam
      int slot = (b * CS + st) * CBEAM + r;
      lp_new[slot] = wval;
      preds_t[slot] = pred;
      bps_t[slot] = bp;
      last_preds[slot] = pred;
      rowmap[slot] = b * CSB + bp;
    }
    __syncthreads();
  }
}

// ---------------- backtrack + write outputs ----------------
__global__ void backtrack_k(const int* __restrict__ preds, const int* __restrict__ bps,
                            const float* __restrict__ lpfin, float* __restrict__ out) {
  int b = blockIdx.x, j = threadIdx.x;
  if (j >= CSB) return;
  int s = j / CBEAM, bm = j % CBEAM;
  int obase = ((b * CS + s) * CBEAM + bm) * CT;
  int tok = preds[(CT - 1) * CNR + b * CSB + j];
  out[obase + CT - 1] = (float)tok;
  int cur = bps[(CT - 2) * CNR + b * CSB + j];
  for (int t = CT - 2; t >= 1; --t) {
    tok = preds[t * CNR + b * CSB + cur];
    out[obase + t] = (float)tok;
    cur = bps[(t - 1) * CNR + b * CSB + cur];
  }
  tok = preds[0 * CNR + b * CSB + cur];
  out[obase + 0] = (float)tok;
  out[CB * CS * CBEAM * CT + b * CSB + j] = lpfin[b * CSB + j];
}

}  // namespace

extern "C" void kernel_launch(void* const* d_in, const int* in_sizes, int n_in,
                              void* d_out, int out_size, void* d_ws, size_t ws_size,
                              hipStream_t stream) {
  (void)in_sizes; (void)n_in; (void)out_size; (void)ws_size;
  const float* img = (const float*)d_in[0];
  const int* startp = (const int*)d_in[1];
  const void* straw = d_in[2];
  const float* emb = (const float*)d_in[3];
  const float* Wh = (const float*)d_in[4];
  const float* Wim = (const float*)d_in[5];
  const float* Wout = (const float*)d_in[6];
  float* out = (float*)d_out;

  char* ws = (char*)d_ws;
  size_t off = 0;
  auto take = [&](size_t bytes) -> char* {
    char* p = ws + off;
    off += (bytes + 255) & ~(size_t)255;
    return p;
  };
  unsigned char* maskbuf = (unsigned char*)take((size_t)CNM);
  int* modep = (int*)take(256);
  float* imgproj = (float*)take((size_t)CB * CH * 4);
  float* H0 = (float*)take((size_t)CNR * CH * 4);
  float* H1 = (float*)take((size_t)CNR * CH * 4);
  float* logits = (float*)take((size_t)CNR * CV * 4);
  float* lsebuf = (float*)take((size_t)CNR * 4);
  float* LP0 = (float*)take((size_t)CNR * 4);
  float* LP1 = (float*)take((size_t)CNR * 4);
  int* lastp = (int*)take((size_t)CNR * 4);
  int* rowmap = (int*)take((size_t)CNR * 4);
  float* toplp = (float*)take((size_t)2560 * 5 * 4);
  int* topcls = (int*)take((size_t)2560 * 5 * 4);
  int* predsq = (int*)take((size_t)CT * CNR * 4);
  int* bpsq = (int*)take((size_t)(CT - 1) * CNR * 4);

  detect_mode_k<<<1, 64, 0, stream>>>((const unsigned int*)straw, modep);
  convert_mask_k<<<2048, 256, 0, stream>>>(straw, maskbuf, modep);
  img_proj_k<<<CB, 256, 0, stream>>>(img, Wim, imgproj);
  init_h_k<<<CB, 256, 0, stream>>>(emb, startp, imgproj, H0);
  gemm_k<128, 128, 32, 8, 8, 0><<<dim3(157, 1), 256, 0, stream>>>(
      H0, nullptr, Wout, logits, CB, CV, CH, nullptr, nullptr, nullptr);
  lse_k<<<CB, 256, 0, stream>>>(logits, lsebuf);
  topk_k<true><<<CB * CS, 256, 0, stream>>>(logits, lsebuf, maskbuf, nullptr, nullptr,
                                            nullptr, LP0, predsq, lastp, rowmap);
  for (int t = 1; t < CT; ++t) {
    float* hprev = (t & 1) ? H0 : H1;
    float* hcur = (t & 1) ? H1 : H0;
    float* lpold = (t & 1) ? LP0 : LP1;
    float* lpnew = (t & 1) ? LP1 : LP0;
    gemm_k<32, 64, 32, 2, 4, 1><<<dim3(8, 20), 256, 0, stream>>>(
        hprev, rowmap, Wh, hcur, CNR, CH, CH, lastp, emb, imgproj);
    gemm_k<128, 128, 32, 8, 8, 0><<<dim3(157, 5), 256, 0, stream>>>(
        hcur, nullptr, Wout, logits, CNR, CV, CH, nullptr, nullptr, nullptr);
    lse_k<<<CNR, 256, 0, stream>>>(logits, lsebuf);
    topk_k<false><<<2560, 256, 0, stream>>>(logits, lsebuf, maskbuf, lastp, toplp, topcls,
                                            nullptr, nullptr, nullptr, nullptr);
    beam_sel_k<<<CB * CS, 128, 0, stream>>>(toplp, topcls, lpold, lpnew, lastp, rowmap,
                                            predsq + (size_t)t * CNR,
                                            bpsq + (size_t)(t - 1) * CNR);
  }
  backtrack_k<<<CB, 32, 0, stream>>>(predsq, bpsq, LP1, out);
}

// Round 2
// 6675.474 us; speedup vs baseline: 2.1999x; 2.1999x over previous
//
#include <hip/hip_runtime.h>
#include <hip/hip_bf16.h>
#include <stdint.h>
#include <stddef.h>

namespace {

constexpr int CB = 32;                  // batch
constexpr int CS = 4;                   // states
constexpr int CV = 20000;               // vocab
constexpr int CH = 512;                 // hidden
constexpr int CBEAM = 5;
constexpr int CT = 20;                  // MAX_STEPS
constexpr int CNR = CB * CS * CBEAM;    // 640 rows
constexpr int CSB = CS * CBEAM;         // 20
constexpr int CNM = CB * CS * CS * CV;  // 10,240,000 mask elems
constexpr int CNP = CB * CS * CV;       // 2,560,000 packed mask bytes
constexpr float VNF = -1e20f;
constexpr float NEGINF = -3.402823466e+38f;
constexpr int IMAX = 0x7fffffff;

// ---------------- state_transform dtype detection ----------------
// modes: 0=u8/bool bytes, 1=int32, 2=int64(low word), 3=float32
__global__ void detect_mode_k(const unsigned int* __restrict__ w, int* __restrict__ mode) {
  if (threadIdx.x != 0 || blockIdx.x != 0) return;
  int all01 = 1, odd1 = 0, f1 = 0;
  for (int i = 0; i < 256; ++i) {
    unsigned int x = w[i];
    if (x > 1u) all01 = 0;
    if ((i & 1) && x == 1u) odd1++;
    if (x == 0x3f800000u) f1++;
  }
  int md;
  if (f1 > 128) md = 3;
  else if (all01) md = (odd1 > 8) ? 1 : 2;
  else md = 0;
  *mode = md;
}

// pack mask nibbles: pm[(b*CS+ss)*CV + v] bit st = state_transform[b,ss,st,v] != 0
__global__ void convert_pack_k(const void* __restrict__ st, unsigned char* __restrict__ pm,
                               const int* __restrict__ mode) {
  int md = *mode;
  for (int i = blockIdx.x * blockDim.x + threadIdx.x; i < CNP; i += gridDim.x * blockDim.x) {
    int v = i % CV;
    int bs = i / CV;
    size_t base = (size_t)bs * 4 * CV + v;
    unsigned char r = 0;
#pragma unroll
    for (int s = 0; s < 4; ++s) {
      size_t idx = base + (size_t)s * CV;
      unsigned char bit;
      if (md == 0)      bit = ((const unsigned char*)st)[idx] != 0;
      else if (md == 1) bit = ((const unsigned int*)st)[idx] != 0;
      else if (md == 2) bit = ((const unsigned int*)st)[2 * idx] != 0;
      else              bit = (((const unsigned int*)st)[idx] & 0x7fffffffu) != 0;
      r |= (unsigned char)(bit << s);
    }
    pm[i] = r;
  }
}

// ---------------- img @ W_im (step-invariant) ----------------
__global__ __launch_bounds__(256) void img_proj_k(const float* __restrict__ img,
                                                  const float* __restrict__ Wim,
                                                  float* __restrict__ out) {
  int b = blockIdx.x, tid = threadIdx.x;
  __shared__ float simg[2048];
  for (int i = tid; i < 2048; i += 256) simg[i] = img[b * 2048 + i];
  __syncthreads();
  int c0 = tid * 2;
  float a0 = 0.f, a1 = 0.f;
  for (int k = 0; k < 2048; ++k) {
    float x = simg[k];
    float2 w = *(const float2*)&Wim[(size_t)k * CH + c0];
    a0 = fmaf(x, w.x, a0);
    a1 = fmaf(x, w.y, a1);
  }
  out[b * CH + c0] = a0;
  out[b * CH + c0 + 1] = a1;
}

// ---------------- h0 = tanh(emb[start] + img_proj) ----------------
__global__ void init_h_k(const float* __restrict__ emb, const int* __restrict__ start,
                         const float* __restrict__ imgp, float* __restrict__ H0) {
  int b = blockIdx.x, tid = threadIdx.x;
  int tok = start[b];
  for (int c = tid; c < CH; c += 256)
    H0[b * CH + c] = tanhf(emb[(size_t)tok * CH + c] + imgp[b * CH + c]);
}

// ---------------- generic tiled f32 GEMM, optional row gather + tanh/emb/img epilogue ----
template <int BM, int BN, int KB, int MT, int NT, int EPI>
__global__ __launch_bounds__(256) void gemm_k(
    const float* __restrict__ A, const int* __restrict__ rowmap,
    const float* __restrict__ Bm, float* __restrict__ C,
    int M, int N, int K,
    const int* __restrict__ tok, const float* __restrict__ emb,
    const float* __restrict__ imgp) {
  constexpr int TX = BN / NT;
  constexpr int TY = BM / MT;
  static_assert(TX * TY == 256, "thread count");
  static_assert((BM * KB / 4) % 256 == 0 && (KB * BN / 4) % 256 == 0, "stage");
  __shared__ float As[KB][BM + 4];
  __shared__ float Bs[KB][BN + 4];
  const int bm = blockIdx.y * BM;
  const int bn = blockIdx.x * BN;
  const int tid = threadIdx.x;
  const int tx = tid % TX, ty = tid / TX;
  float acc[MT][NT];
#pragma unroll
  for (int i = 0; i < MT; ++i)
#pragma unroll
    for (int j = 0; j < NT; ++j) acc[i][j] = 0.f;

  for (int k0 = 0; k0 < K; k0 += KB) {
    constexpr int AIT = BM * KB / 4 / 256;
#pragma unroll
    for (int it = 0; it < AIT; ++it) {
      int i = tid + it * 256;
      int r = i / (KB / 4);
      int kq = i % (KB / 4);
      int row = bm + r;
      float4 v = make_float4(0.f, 0.f, 0.f, 0.f);
      if (row < M) {
        int sr = rowmap ? rowmap[row] : row;
        v = *(const float4*)&A[(size_t)sr * K + k0 + kq * 4];
      }
      As[kq * 4 + 0][r] = v.x;
      As[kq * 4 + 1][r] = v.y;
      As[kq * 4 + 2][r] = v.z;
      As[kq * 4 + 3][r] = v.w;
    }
    constexpr int BIT = KB * BN / 4 / 256;
#pragma unroll
    for (int it = 0; it < BIT; ++it) {
      int i = tid + it * 256;
      int kk = i / (BN / 4);
      int cq = i % (BN / 4);
      int col = bn + cq * 4;
      float4 v = make_float4(0.f, 0.f, 0.f, 0.f);
      if (col < N) v = *(const float4*)&Bm[(size_t)(k0 + kk) * N + col];
      *(float4*)&Bs[kk][cq * 4] = v;
    }
    __syncthreads();
#pragma unroll 8
    for (int kk = 0; kk < KB; ++kk) {
      float a[MT], bb[NT];
#pragma unroll
      for (int i = 0; i < MT; ++i) a[i] = As[kk][ty * MT + i];
#pragma unroll
      for (int j = 0; j < NT; ++j) bb[j] = Bs[kk][tx * NT + j];
#pragma unroll
      for (int i = 0; i < MT; ++i)
#pragma unroll
        for (int j = 0; j < NT; ++j) acc[i][j] = fmaf(a[i], bb[j], acc[i][j]);
    }
    __syncthreads();
  }
#pragma unroll
  for (int i = 0; i < MT; ++i) {
    int row = bm + ty * MT + i;
    if (row < M) {
#pragma unroll
      for (int j4 = 0; j4 < NT / 4; ++j4) {
        int col = bn + tx * NT + j4 * 4;
        if (col < N) {
          float4 v;
          v.x = acc[i][j4 * 4 + 0];
          v.y = acc[i][j4 * 4 + 1];
          v.z = acc[i][j4 * 4 + 2];
          v.w = acc[i][j4 * 4 + 3];
          if (EPI == 1) {
            size_t eb = (size_t)tok[row] * N;
            int ib = (row / CSB) * N;
            v.x = tanhf(v.x + emb[eb + col + 0] + imgp[ib + col + 0]);
            v.y = tanhf(v.y + emb[eb + col + 1] + imgp[ib + col + 1]);
            v.z = tanhf(v.z + emb[eb + col + 2] + imgp[ib + col + 2]);
            v.w = tanhf(v.w + emb[eb + col + 3] + imgp[ib + col + 3]);
          }
          *(float4*)&C[(size_t)row * N + col] = v;
        }
      }
    }
  }
}

// ---------------- per-row logsumexp over V (unchanged numerics) ----------------
__global__ __launch_bounds__(256) void lse_k(const float* __restrict__ logits,
                                             float* __restrict__ lse) {
  int row = blockIdx.x;
  int tid = threadIdx.x;
  const float* lp = logits + (size_t)row * CV;
  __shared__ float red[4];
  float m = NEGINF;
  for (int v = tid * 4; v < CV; v += 1024) {
    float4 x = *(const float4*)(lp + v);
    m = fmaxf(m, fmaxf(fmaxf(x.x, x.y), fmaxf(x.z, x.w)));
  }
#pragma unroll
  for (int off = 32; off > 0; off >>= 1) m = fmaxf(m, __shfl_xor(m, off));
  if ((tid & 63) == 0) red[tid >> 6] = m;
  __syncthreads();
  m = fmaxf(fmaxf(red[0], red[1]), fmaxf(red[2], red[3]));
  __syncthreads();
  float s = 0.f;
  for (int v = tid * 4; v < CV; v += 1024) {
    float4 x = *(const float4*)(lp + v);
    s += expf(x.x - m) + expf(x.y - m) + expf(x.z - m) + expf(x.w - m);
  }
#pragma unroll
  for (int off = 32; off > 0; off >>= 1) s += __shfl_xor(s, off);
  if ((tid & 63) == 0) red[tid >> 6] = s;
  __syncthreads();
  if (tid == 0) lse[row] = m + logf(red[0] + red[1] + red[2] + red[3]);
}

// ---------------- sorted 5-list in named registers ----------------
struct L5 {
  float v0, v1, v2, v3, v4;
  int i0, i1, i2, i3, i4;
};

__device__ __forceinline__ void initL(L5& l) {
  l.v0 = l.v1 = l.v2 = l.v3 = l.v4 = NEGINF;
  l.i0 = l.i1 = l.i2 = l.i3 = l.i4 = IMAX;
}

__device__ __forceinline__ void insL(L5& l, float val, int idx) {
  if (!(val > l.v4)) return;  // strict >: equal values keep earlier (smaller) index first
  if (val > l.v0) {
    l.v4 = l.v3; l.i4 = l.i3; l.v3 = l.v2; l.i3 = l.i2; l.v2 = l.v1; l.i2 = l.i1;
    l.v1 = l.v0; l.i1 = l.i0; l.v0 = val; l.i0 = idx;
  } else if (val > l.v1) {
    l.v4 = l.v3; l.i4 = l.i3; l.v3 = l.v2; l.i3 = l.i2; l.v2 = l.v1; l.i2 = l.i1;
    l.v1 = val; l.i1 = idx;
  } else if (val > l.v2) {
    l.v4 = l.v3; l.i4 = l.i3; l.v3 = l.v2; l.i3 = l.i2; l.v2 = val; l.i2 = idx;
  } else if (val > l.v3) {
    l.v4 = l.v3; l.i4 = l.i3; l.v3 = val; l.i3 = idx;
  } else {
    l.v4 = val; l.i4 = idx;
  }
}

// merge sorted A,B -> top5 into A (val desc, idx asc)
__device__ __forceinline__ void mergeL(L5& A, L5 B) {
  float o0, o1, o2, o3, o4;
  int q0, q1, q2, q3, q4;
#define MSTEP(OV, OI)                                                                    \
  {                                                                                      \
    bool ta = (A.v0 > B.v0) || (A.v0 == B.v0 && A.i0 < B.i0);                            \
    if (ta) {                                                                            \
      OV = A.v0; OI = A.i0;                                                              \
      A.v0 = A.v1; A.i0 = A.i1; A.v1 = A.v2; A.i1 = A.i2; A.v2 = A.v3; A.i2 = A.i3;      \
      A.v3 = A.v4; A.i3 = A.i4; A.v4 = NEGINF; A.i4 = IMAX;                              \
    } else {                                                                             \
      OV = B.v0; OI = B.i0;                                                              \
      B.v0 = B.v1; B.i0 = B.i1; B.v1 = B.v2; B.i1 = B.i2; B.v2 = B.v3; B.i2 = B.i3;      \
      B.v3 = B.v4; B.i3 = B.i4; B.v4 = NEGINF; B.i4 = IMAX;                              \
    }                                                                                    \
  }
  MSTEP(o0, q0) MSTEP(o1, q1) MSTEP(o2, q2) MSTEP(o3, q3) MSTEP(o4, q4)
#undef MSTEP
  A.v0 = o0; A.v1 = o1; A.v2 = o2; A.v3 = o3; A.v4 = o4;
  A.i0 = q0; A.i1 = q1; A.i2 = q2; A.i3 = q3; A.i4 = q4;
}

__device__ __forceinline__ L5 shflxL(const L5& a, int off) {
  L5 r;
  r.v0 = __shfl_xor(a.v0, off); r.v1 = __shfl_xor(a.v1, off); r.v2 = __shfl_xor(a.v2, off);
  r.v3 = __shfl_xor(a.v3, off); r.v4 = __shfl_xor(a.v4, off);
  r.i0 = __shfl_xor(a.i0, off); r.i1 = __shfl_xor(a.i1, off); r.i2 = __shfl_xor(a.i2, off);
  r.i3 = __shfl_xor(a.i3, off); r.i4 = __shfl_xor(a.i4, off);
  return r;
}

// ---------------- fused masked top-5 for all 4 target states, per (row, vocab-half) ----
// grid.x = nrows*2 ; row = blk>>1, half = blk&1
// outputs: hv_lp/hv_cls [row][st][half][5]
template <bool INIT>
__global__ __launch_bounds__(256) void topk_half_k(
    const float* __restrict__ logits, const float* __restrict__ lse,
    const unsigned char* __restrict__ pmask, const int* __restrict__ last_preds,
    float* __restrict__ hv_lp, int* __restrict__ hv_cls) {
  constexpr int HV = CV / 2;   // 10000
  constexpr int NG = HV / 4;   // 2500 float4-groups
  int blk = blockIdx.x;
  int half = blk & 1, row = blk >> 1;
  int b, ss;
  if (INIT) { b = row; ss = 0; }
  else { b = row / CSB; ss = (row / CBEAM) % CS; }
  const int tid = threadIdx.x;
  const unsigned char* prow = pmask + (size_t)(b * CS + ss) * CV;

  if (!INIT && last_preds[row] == 0) {  // ended beam: cleaned = after_end
    if (tid == 0) {
      unsigned char m0 = prow[0];
#pragma unroll
      for (int st = 0; st < 4; ++st) {
        int base = ((row * 4 + st) * 2 + half) * 5;
        if (half == 0) {
          hv_lp[base] = ((m0 >> st) & 1) ? 0.0f : VNF;
          hv_cls[base] = 0;
#pragma unroll
          for (int k = 1; k < 5; ++k) { hv_lp[base + k] = VNF; hv_cls[base + k] = k; }
        } else {
#pragma unroll
          for (int k = 0; k < 5; ++k) { hv_lp[base + k] = VNF; hv_cls[base + k] = HV + k; }
        }
      }
    }
    return;
  }

  const float* lprow = logits + (size_t)row * CV + (size_t)half * HV;
  const unsigned char* ph = prow + (size_t)half * HV;
  float lsev = lse[row];

  L5 lst0, lst1, lst2, lst3;
  initL(lst0); initL(lst1); initL(lst2); initL(lst3);

#define PROC1(VAL, IDX, BITS)                 \
  {                                           \
    if ((BITS) & 1) insL(lst0, VAL, IDX);     \
    if ((BITS) & 2) insL(lst1, VAL, IDX);     \
    if ((BITS) & 4) insL(lst2, VAL, IDX);     \
    if ((BITS) & 8) insL(lst3, VAL, IDX);     \
  }
#define PROC4(X, M, G)                                                        \
  {                                                                           \
    int ibase = half * HV + (G) * 4;                                          \
    float s0 = (X).x - lsev, s1 = (X).y - lsev;                               \
    float s2 = (X).z - lsev, s3 = (X).w - lsev;                               \
    PROC1(s0, ibase + 0, (M))                                                 \
    PROC1(s1, ibase + 1, (M) >> 8)                                            \
    PROC1(s2, ibase + 2, (M) >> 16)                                           \
    PROC1(s3, ibase + 3, (M) >> 24)                                           \
  }

  for (int g = tid; g < NG; g += 512) {
    int g2 = g + 256;
    float4 x0 = *(const float4*)(lprow + (size_t)g * 4);
    unsigned int m0 = *(const unsigned int*)(ph + (size_t)g * 4);
    float4 x1 = make_float4(0.f, 0.f, 0.f, 0.f);
    unsigned int m1 = 0;
    bool has1 = (g2 < NG);
    if (has1) {
      x1 = *(const float4*)(lprow + (size_t)g2 * 4);
      m1 = *(const unsigned int*)(ph + (size_t)g2 * 4);
    }
    PROC4(x0, m0, g)
    if (has1) PROC4(x1, m1, g2)
  }
#undef PROC4
#undef PROC1

  // in-wave butterfly merge (all lanes converge to wave top-5 per st)
#pragma unroll
  for (int off = 1; off < 64; off <<= 1) {
    mergeL(lst0, shflxL(lst0, off));
    mergeL(lst1, shflxL(lst1, off));
    mergeL(lst2, shflxL(lst2, off));
    mergeL(lst3, shflxL(lst3, off));
  }

  // cross-wave: lane 0 of each wave posts its 4 lists; thread 0 merges 4 waves
  __shared__ float swv[4][4][5];
  __shared__ int swi[4][4][5];
  int wid = tid >> 6, lane = tid & 63;
  if (lane == 0) {
#define POST(L, ST)                                                     \
    swv[wid][ST][0] = L.v0; swv[wid][ST][1] = L.v1; swv[wid][ST][2] = L.v2; \
    swv[wid][ST][3] = L.v3; swv[wid][ST][4] = L.v4;                     \
    swi[wid][ST][0] = L.i0; swi[wid][ST][1] = L.i1; swi[wid][ST][2] = L.i2; \
    swi[wid][ST][3] = L.i3; swi[wid][ST][4] = L.i4;
    POST(lst0, 0) POST(lst1, 1) POST(lst2, 2) POST(lst3, 3)
#undef POST
  }
  __syncthreads();
  if (tid == 0) {
#pragma unroll
    for (int st = 0; st < 4; ++st) {
      L5 A;
      A.v0 = swv[0][st][0]; A.v1 = swv[0][st][1]; A.v2 = swv[0][st][2];
      A.v3 = swv[0][st][3]; A.v4 = swv[0][st][4];
      A.i0 = swi[0][st][0]; A.i1 = swi[0][st][1]; A.i2 = swi[0][st][2];
      A.i3 = swi[0][st][3]; A.i4 = swi[0][st][4];
#pragma unroll
      for (int w = 1; w < 4; ++w) {
        L5 Bb;
        Bb.v0 = swv[w][st][0]; Bb.v1 = swv[w][st][1]; Bb.v2 = swv[w][st][2];
        Bb.v3 = swv[w][st][3]; Bb.v4 = swv[w][st][4];
        Bb.i0 = swi[w][st][0]; Bb.i1 = swi[w][st][1]; Bb.i2 = swi[w][st][2];
        Bb.i3 = swi[w][st][3]; Bb.i4 = swi[w][st][4];
        mergeL(A, Bb);
      }
      int base = ((row * 4 + st) * 2 + half) * 5;
      hv_lp[base + 0] = A.v0; hv_lp[base + 1] = A.v1; hv_lp[base + 2] = A.v2;
      hv_lp[base + 3] = A.v3; hv_lp[base + 4] = A.v4;
      hv_cls[base + 0] = A.i0; hv_cls[base + 1] = A.i1; hv_cls[base + 2] = A.i2;
      hv_cls[base + 3] = A.i3; hv_cls[base + 4] = A.i4;
    }
  }
}

// ---------------- merge the two vocab-halves -> reference-ordered top-5 ----------------
template <bool INIT>
__global__ void merge_halves_k(const float* __restrict__ hv_lp, const int* __restrict__ hv_cls,
                               float* __restrict__ top_lp, int* __restrict__ top_cls,
                               float* __restrict__ lp0, int* __restrict__ preds0,
                               int* __restrict__ lastp_out, int* __restrict__ rowmap) {
  int gid = blockIdx.x * blockDim.x + threadIdx.x;
  int nit = (INIT ? CB : CNR) * 4;
  if (gid >= nit) return;
  int row = gid / 4, st = gid % 4;
  const float* a = hv_lp + (size_t)gid * 10;
  const int* ai = hv_cls + (size_t)gid * 10;
  L5 A, Bb;
  A.v0 = a[0]; A.v1 = a[1]; A.v2 = a[2]; A.v3 = a[3]; A.v4 = a[4];
  A.i0 = ai[0]; A.i1 = ai[1]; A.i2 = ai[2]; A.i3 = ai[3]; A.i4 = ai[4];
  Bb.v0 = a[5]; Bb.v1 = a[6]; Bb.v2 = a[7]; Bb.v3 = a[8]; Bb.v4 = a[9];
  Bb.i0 = ai[5]; Bb.i1 = ai[6]; Bb.i2 = ai[7]; Bb.i3 = ai[8]; Bb.i4 = ai[9];
  mergeL(A, Bb);
  if (INIT) {
    int slot = row * CSB + st * 5;  // = b*20 + st*5
    float vv[5] = {A.v0, A.v1, A.v2, A.v3, A.v4};
    int ii[5] = {A.i0, A.i1, A.i2, A.i3, A.i4};
#pragma unroll
    for (int k = 0; k < 5; ++k) {
      lp0[slot + k] = vv[k];
      preds0[slot + k] = ii[k];
      lastp_out[slot + k] = ii[k];
      rowmap[slot + k] = row;
    }
  } else {
    int b = row / CSB, ss = (row / CBEAM) % CS, beam = row % CBEAM;
    int o = (((b * CS + st) * CS + ss) * CBEAM + beam) * 5;
    top_lp[o + 0] = A.v0; top_lp[o + 1] = A.v1; top_lp[o + 2] = A.v2;
    top_lp[o + 3] = A.v3; top_lp[o + 4] = A.v4;
    top_cls[o + 0] = A.i0; top_cls[o + 1] = A.i1; top_cls[o + 2] = A.i2;
    top_cls[o + 3] = A.i3; top_cls[o + 4] = A.i4;
  }
}

// ---------------- beam selection: top-5 of 100 candidates per (b, st) ----------------
__global__ __launch_bounds__(128) void beam_sel_k(
    const float* __restrict__ top_lp, const int* __restrict__ top_cls,
    const float* __restrict__ lp_old, float* __restrict__ lp_new,
    int* __restrict__ last_preds, int* __restrict__ rowmap,
    int* __restrict__ preds_t, int* __restrict__ bps_t) {
  int b = blockIdx.x / CS, st = blockIdx.x % CS;
  int tid = threadIdx.x;
  __shared__ float sv[128];
  __shared__ int si[128];
  float val = NEGINF;
  int idx = IMAX;
  if (tid < 100) {
    int ss = tid / 25, rem = tid % 25;
    int beam = rem / 5, k = rem % 5;
    val = top_lp[(size_t)(((b * CS + st) * CS + ss) * CBEAM + beam) * 5 + k] +
          lp_old[(b * CS + ss) * CBEAM + beam];
    idx = tid;
  }
  for (int r = 0; r < 5; ++r) {
    sv[tid] = val;
    si[tid] = idx;
    __syncthreads();
    for (int off = 64; off > 0; off >>= 1) {
      if (tid < off) {
        float w = sv[tid + off];
        int wi = si[tid + off];
        if (w > sv[tid] || (w == sv[tid] && wi < si[tid])) { sv[tid] = w; si[tid] = wi; }
      }
      __syncthreads();
    }
    float wval = sv[0];
    int widx = si[0];
    if (idx == widx) { val = NEGINF; idx = IMAX; }
    if (tid == r) {
      int ss = widx / 25, rem = widx % 25;
      int beam = rem / 5, k = rem % 5;
      int pred = top_cls[(size_t)(((b * CS + st) * CS + ss) * CBEAM + beam) * 5 + k];
      int bp = widx / 5;  // ss*5+beam
      int slot = (b * CS + st) * CBEAM + r;
      lp_new[slot] = wval;
      preds_t[slot] = pred;
      bps_t[slot] = bp;
      last_preds[slot] = pred;
      rowmap[slot] = b * CSB + bp;
    }
    __syncthreads();
  }
}

// ---------------- backtrack + write outputs ----------------
__global__ void backtrack_k(const int* __restrict__ preds, const int* __restrict__ bps,
                            const float* __restrict__ lpfin, float* __restrict__ out) {
  int b = blockIdx.x, j = threadIdx.x;
  if (j >= CSB) return;
  int s = j / CBEAM, bm = j % CBEAM;
  int obase = ((b * CS + s) * CBEAM + bm) * CT;
  int tok = preds[(CT - 1) * CNR + b * CSB + j];
  out[obase + CT - 1] = (float)tok;
  int cur = bps[(CT - 2) * CNR + b * CSB + j];
  for (int t = CT - 2; t >= 1; --t) {
    tok = preds[t * CNR + b * CSB + cur];
    out[obase + t] = (float)tok;
    cur = bps[(t - 1) * CNR + b * CSB + cur];
  }
  tok = preds[0 * CNR + b * CSB + cur];
  out[obase + 0] = (float)tok;
  out[CB * CS * CBEAM * CT + b * CSB + j] = lpfin[b * CSB + j];
}

}  // namespace

extern "C" void kernel_launch(void* const* d_in, const int* in_sizes, int n_in,
                              void* d_out, int out_size, void* d_ws, size_t ws_size,
                              hipStream_t stream) {
  (void)in_sizes; (void)n_in; (void)out_size; (void)ws_size;
  const float* img = (const float*)d_in[0];
  const int* startp = (const int*)d_in[1];
  const void* straw = d_in[2];
  const float* emb = (const float*)d_in[3];
  const float* Wh = (const float*)d_in[4];
  const float* Wim = (const float*)d_in[5];
  const float* Wout = (const float*)d_in[6];
  float* out = (float*)d_out;

  char* ws = (char*)d_ws;
  size_t off = 0;
  auto take = [&](size_t bytes) -> char* {
    char* p = ws + off;
    off += (bytes + 255) & ~(size_t)255;
    return p;
  };
  unsigned char* pmask = (unsigned char*)take((size_t)CNP);
  int* modep = (int*)take(256);
  float* imgproj = (float*)take((size_t)CB * CH * 4);
  float* H0 = (float*)take((size_t)CNR * CH * 4);
  float* H1 = (float*)take((size_t)CNR * CH * 4);
  float* logits = (float*)take((size_t)CNR * CV * 4);
  float* lsebuf = (float*)take((size_t)CNR * 4);
  float* LP0 = (float*)take((size_t)CNR * 4);
  float* LP1 = (float*)take((size_t)CNR * 4);
  int* lastp = (int*)take((size_t)CNR * 4);
  int* rowmap = (int*)take((size_t)CNR * 4);
  float* toplp = (float*)take((size_t)2560 * 5 * 4);
  int* topcls = (int*)take((size_t)2560 * 5 * 4);
  float* hvlp = (float*)take((size_t)CNR * 4 * 2 * 5 * 4);
  int* hvcls = (int*)take((size_t)CNR * 4 * 2 * 5 * 4);
  int* predsq = (int*)take((size_t)CT * CNR * 4);
  int* bpsq = (int*)take((size_t)(CT - 1) * CNR * 4);

  detect_mode_k<<<1, 64, 0, stream>>>((const unsigned int*)straw, modep);
  convert_pack_k<<<1024, 256, 0, stream>>>(straw, pmask, modep);
  img_proj_k<<<CB, 256, 0, stream>>>(img, Wim, imgproj);
  init_h_k<<<CB, 256, 0, stream>>>(emb, startp, imgproj, H0);
  gemm_k<128, 128, 32, 8, 8, 0><<<dim3(157, 1), 256, 0, stream>>>(
      H0, nullptr, Wout, logits, CB, CV, CH, nullptr, nullptr, nullptr);
  lse_k<<<CB, 256, 0, stream>>>(logits, lsebuf);
  topk_half_k<true><<<CB * 2, 256, 0, stream>>>(logits, lsebuf, pmask, nullptr, hvlp, hvcls);
  merge_halves_k<true><<<1, 128, 0, stream>>>(hvlp, hvcls, nullptr, nullptr, LP0, predsq,
                                              lastp, rowmap);
  for (int t = 1; t < CT; ++t) {
    float* hprev = (t & 1) ? H0 : H1;
    float* hcur = (t & 1) ? H1 : H0;
    float* lpold = (t & 1) ? LP0 : LP1;
    float* lpnew = (t & 1) ? LP1 : LP0;
    gemm_k<32, 64, 32, 2, 4, 1><<<dim3(8, 20), 256, 0, stream>>>(
        hprev, rowmap, Wh, hcur, CNR, CH, CH, lastp, emb, imgproj);
    gemm_k<128, 128, 32, 8, 8, 0><<<dim3(157, 5), 256, 0, stream>>>(
        hcur, nullptr, Wout, logits, CNR, CV, CH, nullptr, nullptr, nullptr);
    lse_k<<<CNR, 256, 0, stream>>>(logits, lsebuf);
    topk_half_k<false><<<CNR * 2, 256, 0, stream>>>(logits, lsebuf, pmask, lastp, hvlp, hvcls);
    merge_halves_k<false><<<10, 256, 0, stream>>>(hvlp, hvcls, toplp, topcls, nullptr,
                                                  nullptr, nullptr, nullptr);
    beam_sel_k<<<CB * CS, 128, 0, stream>>>(toplp, topcls, lpold, lpnew, lastp, rowmap,
                                            predsq + (size_t)t * CNR,
                                            bpsq + (size_t)(t - 1) * CNR);
  }
  backtrack_k<<<CB, 32, 0, stream>>>(predsq, bpsq, LP1, out);
}